// Round 1
// baseline (519.497 us; speedup 1.0000x reference)
//
#include <hip/hip_runtime.h>
#include <math.h>

#define B_    8
#define N_    1024
#define FIN   512
#define FOUT  256
#define ALPHA 0.2f
#define NEGV  (-9.0e15f)
#define EPSV  1e-5f

__device__ __forceinline__ float gelu_exact(float x) {
    return 0.5f * x * (1.0f + erff(x * 0.70710678118654752f));
}

// Kernel 1: Wh = h @ W  (8192x512 @ 512x256), fused F1 = Wh@a1, F2 = Wh@a2.
// Block = 256 threads = 16 rows x 16 feature-groups(16 wide). Grid = 512.
__global__ __launch_bounds__(256) void k_gemm(const float* __restrict__ h,
                                              const float* __restrict__ W,
                                              const float* __restrict__ a,
                                              float* __restrict__ Wh,
                                              float* __restrict__ F1,
                                              float* __restrict__ F2) {
    const int tid = threadIdx.x;
    const int r   = tid >> 4;          // 0..15 row within block
    const int fg  = tid & 15;          // feature group
    const int f0  = fg * 16;
    const long row = (long)blockIdx.x * 16 + r;   // 0..8191
    const float* hrow = h + row * FIN;

    float acc[16] = {};
    for (int k = 0; k < FIN; k += 4) {
        const float4 hv4 = *(const float4*)(hrow + k);
        const float hv[4] = {hv4.x, hv4.y, hv4.z, hv4.w};
        #pragma unroll
        for (int kk = 0; kk < 4; ++kk) {
            const float* wrow = W + (long)(k + kk) * FOUT + f0;
            #pragma unroll
            for (int u = 0; u < 4; ++u) {
                const float4 wv = *(const float4*)(wrow + u * 4);
                acc[u*4+0] += hv[kk] * wv.x;
                acc[u*4+1] += hv[kk] * wv.y;
                acc[u*4+2] += hv[kk] * wv.z;
                acc[u*4+3] += hv[kk] * wv.w;
            }
        }
    }

    float* whrow = Wh + row * FOUT + f0;
    #pragma unroll
    for (int u = 0; u < 4; ++u) {
        float4 v;
        v.x = acc[u*4+0]; v.y = acc[u*4+1]; v.z = acc[u*4+2]; v.w = acc[u*4+3];
        *(float4*)(whrow + u*4) = v;
    }

    // f1/f2 partial dots over this thread's 16 features, then 16-lane reduce
    float v1 = 0.f, v2 = 0.f;
    #pragma unroll
    for (int u = 0; u < 16; ++u) {
        v1 += acc[u] * a[f0 + u];
        v2 += acc[u] * a[FOUT + f0 + u];
    }
    #pragma unroll
    for (int off = 1; off < 16; off <<= 1) {
        v1 += __shfl_xor(v1, off, 64);
        v2 += __shfl_xor(v2, off, 64);
    }
    if (fg == 0) { F1[row] = v1; F2[row] = v2; }
}

// Kernel 2: masked rank-1-logit softmax + att@Wh + LayerNorm + GELU.
// Block = 256 threads handles 16 rows of one batch. Grid = (64, 8).
__global__ __launch_bounds__(256) void k_attn(const float* __restrict__ Wh,
                                              const float* __restrict__ adj,
                                              const float* __restrict__ F1,
                                              const float* __restrict__ F2,
                                              const float* __restrict__ gamma,
                                              const float* __restrict__ beta,
                                              float* __restrict__ out) {
    const int tid = threadIdx.x;
    const int b   = blockIdx.y;
    const int i0  = blockIdx.x * 16;

    __shared__ float f2s[N_];
    __shared__ float m_s[16], il_s[16], f1_s[16];

    for (int j = tid; j < N_; j += 256) f2s[j] = F2[b * N_ + j];
    __syncthreads();

    const float* adjb = adj + ((long)b * N_ + i0) * N_;
    const int wave = tid >> 6, lane = tid & 63;

    // ---- pass 1: per-row masked softmax max & sum (wave per row) ----
    for (int rr = wave; rr < 16; rr += 4) {
        const float f1 = F1[b * N_ + i0 + rr];
        const float* arow = adjb + (long)rr * N_;
        float m = -INFINITY, s = 0.f;
        for (int j = lane; j < N_; j += 64) {
            float av = arow[j];
            float x = f1 + f2s[j];
            x = (x > 0.f) ? x : ALPHA * x;
            float e = (av > 0.f) ? x : NEGV;
            float mn = fmaxf(m, e);
            s = s * __expf(m - mn) + __expf(e - mn);
            m = mn;
        }
        #pragma unroll
        for (int off = 32; off; off >>= 1) {
            float m2 = __shfl_xor(m, off, 64);
            float s2 = __shfl_xor(s, off, 64);
            float mn = fmaxf(m, m2);
            s = s * __expf(m - mn) + s2 * __expf(m2 - mn);
            m = mn;
        }
        if (lane == 0) { m_s[rr] = m; il_s[rr] = 1.0f / s; f1_s[rr] = f1; }
    }
    __syncthreads();

    // ---- pass 2: O = softmax(e) @ Wh, thread = (row, 16 features) ----
    const int r  = tid >> 4;
    const int f0 = (tid & 15) * 16;
    const float m_r  = m_s[r];
    const float f1r  = f1_s[r];
    const bool allmask = (m_r == NEGV);     // fully masked row -> uniform
    const float* arow = adjb + (long)r * N_;
    const float* whb  = Wh + (long)b * N_ * FOUT;

    float acc[16] = {};
    for (int j = 0; j < N_; ++j) {
        float av = arow[j];
        if ((av > 0.f) || allmask) {
            float w;
            if (allmask) {
                w = 1.0f;
            } else {
                float x = f1r + f2s[j];
                x = (x > 0.f) ? x : ALPHA * x;
                w = __expf(x - m_r);
            }
            const float* whr = whb + (long)j * FOUT + f0;
            #pragma unroll
            for (int u = 0; u < 4; ++u) {
                const float4 wv = *(const float4*)(whr + u * 4);
                acc[u*4+0] += w * wv.x;
                acc[u*4+1] += w * wv.y;
                acc[u*4+2] += w * wv.z;
                acc[u*4+3] += w * wv.w;
            }
        }
    }

    // ---- epilogue: scale by 1/l, LayerNorm over 256 feats (16 lanes), GELU ----
    const float il = il_s[r];
    #pragma unroll
    for (int u = 0; u < 16; ++u) acc[u] *= il;

    float s1 = 0.f, s2 = 0.f;
    #pragma unroll
    for (int u = 0; u < 16; ++u) { s1 += acc[u]; s2 += acc[u] * acc[u]; }
    #pragma unroll
    for (int off = 1; off < 16; off <<= 1) {
        s1 += __shfl_xor(s1, off, 64);
        s2 += __shfl_xor(s2, off, 64);
    }
    const float mean = s1 * (1.0f / FOUT);
    const float var  = s2 * (1.0f / FOUT) - mean * mean;
    const float rstd = rsqrtf(var + EPSV);

    float* orow = out + ((long)(b * N_ + i0 + r)) * FOUT + f0;
    #pragma unroll
    for (int u = 0; u < 4; ++u) {
        const float4 g  = *(const float4*)(gamma + f0 + u * 4);
        const float4 bt = *(const float4*)(beta  + f0 + u * 4);
        float4 o;
        o.x = gelu_exact((acc[u*4+0] - mean) * rstd * g.x + bt.x);
        o.y = gelu_exact((acc[u*4+1] - mean) * rstd * g.y + bt.y);
        o.z = gelu_exact((acc[u*4+2] - mean) * rstd * g.z + bt.z);
        o.w = gelu_exact((acc[u*4+3] - mean) * rstd * g.w + bt.w);
        *(float4*)(orow + u * 4) = o;
    }
}

extern "C" void kernel_launch(void* const* d_in, const int* in_sizes, int n_in,
                              void* d_out, int out_size, void* d_ws, size_t ws_size,
                              hipStream_t stream) {
    const float* h     = (const float*)d_in[0];
    const float* adj   = (const float*)d_in[1];
    // d_in[2]=q_type, d_in[3]=pos : unused scalars
    const float* W     = (const float*)d_in[4];
    const float* a     = (const float*)d_in[5];
    const float* gamma = (const float*)d_in[6];
    const float* beta  = (const float*)d_in[7];
    float* out = (float*)d_out;

    float* Wh = (float*)d_ws;                         // 8192*256 floats
    float* F1 = Wh + (size_t)B_ * N_ * FOUT;          // 8192 floats
    float* F2 = F1 + (size_t)B_ * N_;                 // 8192 floats

    k_gemm<<<dim3(B_ * N_ / 16), 256, 0, stream>>>(h, W, a, Wh, F1, F2);
    k_attn<<<dim3(N_ / 16, B_), 256, 0, stream>>>(Wh, adj, F1, F2, gamma, beta, out);
}

// Round 2
// 86.702 us; speedup vs baseline: 5.9917x; 5.9917x over previous
//
#include <hip/hip_runtime.h>
#include <math.h>

#define B_    8
#define N_    1024
#define FIN   512
#define FOUT  256
#define ALPHA 0.2f
#define NEGV  (-9.0e15f)
#define EPSV  1e-5f

__device__ __forceinline__ float gelu_exact(float x) {
    return 0.5f * x * (1.0f + erff(x * 0.70710678118654752f));
}

// ---------------------------------------------------------------------------
// Kernel 1: Wh = h @ W  (8192x512 @ 512x256) + fused F1 = Wh@a1, F2 = Wh@a2.
// LDS-tiled fp32 GEMM. Block = 256 thr; tile BM=16 rows x 256 cols; K-chunk 16.
// Thread = (cg = tid&63 -> cols cg*4..+3, rg = tid>>6 -> rows rg*4..+3).
// Grid = 512 blocks.
// ---------------------------------------------------------------------------
#define BM 16
#define KC 16
__global__ __launch_bounds__(256) void k_gemm(const float* __restrict__ h,
                                              const float* __restrict__ W,
                                              const float* __restrict__ a,
                                              float* __restrict__ Wh,
                                              float* __restrict__ F1,
                                              float* __restrict__ F2) {
    const int tid = threadIdx.x;
    const int cg  = tid & 63;
    const int rg  = tid >> 6;
    const long row0 = (long)blockIdx.x * BM;

    __shared__ float Ws[KC][FOUT];   // 16 KB
    __shared__ float hs[BM][KC];     // 1 KB

    float acc[4][4] = {};

    for (int k0 = 0; k0 < FIN; k0 += KC) {
        __syncthreads();
        // stage W chunk: 16x256 floats = 1024 float4, 4 per thread, coalesced
        #pragma unroll
        for (int i = 0; i < 4; ++i) {
            int q  = tid + 256 * i;
            int wr = q >> 6;
            int wc = (q & 63) * 4;
            *(float4*)&Ws[wr][wc] = *(const float4*)(W + (long)(k0 + wr) * FOUT + wc);
        }
        // stage h tile: 16x16 floats, 1 per thread
        {
            int hr = tid >> 4, hk = tid & 15;
            hs[hr][hk] = h[(row0 + hr) * FIN + k0 + hk];
        }
        __syncthreads();

        #pragma unroll
        for (int kk = 0; kk < KC; kk += 4) {
            float4 hh[4], wv[4];
            #pragma unroll
            for (int ri = 0; ri < 4; ++ri) hh[ri] = *(const float4*)&hs[rg*4 + ri][kk];
            #pragma unroll
            for (int kq = 0; kq < 4; ++kq) wv[kq] = *(const float4*)&Ws[kk + kq][cg*4];
            #pragma unroll
            for (int ri = 0; ri < 4; ++ri) {
                const float hr4[4] = {hh[ri].x, hh[ri].y, hh[ri].z, hh[ri].w};
                #pragma unroll
                for (int kq = 0; kq < 4; ++kq) {
                    acc[ri][0] += hr4[kq] * wv[kq].x;
                    acc[ri][1] += hr4[kq] * wv[kq].y;
                    acc[ri][2] += hr4[kq] * wv[kq].z;
                    acc[ri][3] += hr4[kq] * wv[kq].w;
                }
            }
        }
    }

    // store Wh (coalesced: 64 lanes cover one full 1KB row per instr)
    #pragma unroll
    for (int ri = 0; ri < 4; ++ri) {
        float4 v;
        v.x = acc[ri][0]; v.y = acc[ri][1]; v.z = acc[ri][2]; v.w = acc[ri][3];
        *(float4*)(Wh + (row0 + rg*4 + ri) * FOUT + cg*4) = v;
    }

    // fused F1/F2: per-row dot with a1/a2, full-wave (64-lane) reduce
    float a1v[4], a2v[4];
    #pragma unroll
    for (int ci = 0; ci < 4; ++ci) {
        a1v[ci] = a[cg*4 + ci];
        a2v[ci] = a[FOUT + cg*4 + ci];
    }
    #pragma unroll
    for (int ri = 0; ri < 4; ++ri) {
        float p1 = 0.f, p2 = 0.f;
        #pragma unroll
        for (int ci = 0; ci < 4; ++ci) {
            p1 += acc[ri][ci] * a1v[ci];
            p2 += acc[ri][ci] * a2v[ci];
        }
        #pragma unroll
        for (int off = 1; off < 64; off <<= 1) {
            p1 += __shfl_xor(p1, off, 64);
            p2 += __shfl_xor(p2, off, 64);
        }
        if (cg == 0) {
            F1[row0 + rg*4 + ri] = p1;
            F2[row0 + rg*4 + ri] = p2;
        }
    }
}

// ---------------------------------------------------------------------------
// Kernel 2: single-pass online-softmax attention + att@Wh + LayerNorm + GELU.
// Block = 256 thr = 8 rows x 32 lanes (half-wave per row). Grid = (128, 8).
// Per 256-col chunk: compact nonzero (j, logit) into half-wave-private LDS
// lists (same-wave LDS ops are in-order -> no __syncthreads), flash-style
// rescale, then gather-accumulate w * Wh[j, f0..f0+7].
// ---------------------------------------------------------------------------
__global__ __launch_bounds__(256) void k_attn(const float* __restrict__ Wh,
                                              const float* __restrict__ adj,
                                              const float* __restrict__ F1,
                                              const float* __restrict__ F2,
                                              const float* __restrict__ gamma,
                                              const float* __restrict__ beta,
                                              float* __restrict__ out) {
    const int tid = threadIdx.x;
    const int b   = blockIdx.y;
    const int i0  = blockIdx.x * 8;
    const int r   = tid >> 5;        // row within block (half-wave)
    const int sub = tid & 31;        // lane within row
    const int f0  = sub * 8;         // 8 features per lane

    __shared__ float f2s[N_];        // 4 KB
    __shared__ int   cnt[8];
    __shared__ int   jl[8][256];     // 8 KB
    __shared__ float xl[8][256];     // 8 KB

    {
        int j = tid * 4;
        *(float4*)&f2s[j] = *(const float4*)(F2 + b * N_ + j);
    }
    __syncthreads();

    const float f1r = F1[b * N_ + i0 + r];
    const float* __restrict__ arow = adj + ((long)b * N_ + i0 + r) * N_;
    const float* __restrict__ whb  = Wh + (long)b * N_ * FOUT + f0;

    float m = -INFINITY, l = 0.f;
    float acc[8] = {};

    for (int c0 = 0; c0 < N_; c0 += 256) {
        if (sub == 0) cnt[r] = 0;
        // --- compact: each lane scans 8 cols of its row ---
        float lm = -INFINITY;
        const int base_j = c0 + sub * 8;
        #pragma unroll
        for (int t = 0; t < 8; t += 4) {
            float4 av = *(const float4*)(arow + base_j + t);
            float aa[4] = {av.x, av.y, av.z, av.w};
            #pragma unroll
            for (int u = 0; u < 4; ++u) {
                if (aa[u] > 0.f) {
                    int j = base_j + t + u;
                    float x = f1r + f2s[j];
                    x = (x > 0.f) ? x : ALPHA * x;
                    int p = atomicAdd(&cnt[r], 1);
                    jl[r][p] = j;
                    xl[r][p] = x;
                    lm = fmaxf(lm, x);
                }
            }
        }
        // chunk max across the 32 lanes of this row (stays within half-wave)
        #pragma unroll
        for (int off = 16; off; off >>= 1)
            lm = fmaxf(lm, __shfl_xor(lm, off, 64));
        int n = cnt[r];   // same-wave DS ordering: all 32 lanes' pushes visible

        if (lm > m) {     // online rescale (m=-inf -> factor 0, acc already 0)
            float f = __expf(m - lm);
            l *= f;
            #pragma unroll
            for (int u = 0; u < 8; ++u) acc[u] *= f;
            m = lm;
        }
        // --- gather-accumulate over compacted nonzeros ---
        for (int k = 0; k < n; ++k) {
            int   j = jl[r][k];
            float w = __expf(xl[r][k] - m);
            l += w;
            const float* p = whb + (long)j * FOUT;
            float4 v0 = *(const float4*)(p);
            float4 v1 = *(const float4*)(p + 4);
            acc[0] += w * v0.x; acc[1] += w * v0.y;
            acc[2] += w * v0.z; acc[3] += w * v0.w;
            acc[4] += w * v1.x; acc[5] += w * v1.y;
            acc[6] += w * v1.z; acc[7] += w * v1.w;
        }
    }

    if (l == 0.f) {   // fully-masked row: reference softmax is uniform 1/N
        for (int j = 0; j < N_; ++j) {
            const float* p = whb + (long)j * FOUT;
            float4 v0 = *(const float4*)(p);
            float4 v1 = *(const float4*)(p + 4);
            acc[0] += v0.x; acc[1] += v0.y; acc[2] += v0.z; acc[3] += v0.w;
            acc[4] += v1.x; acc[5] += v1.y; acc[6] += v1.z; acc[7] += v1.w;
        }
        l = (float)N_;
    }

    // --- epilogue: normalize, LayerNorm over 256 feats (32 lanes), GELU ---
    const float il = 1.0f / l;
    float s1 = 0.f, s2 = 0.f;
    #pragma unroll
    for (int u = 0; u < 8; ++u) {
        acc[u] *= il;
        s1 += acc[u];
        s2 += acc[u] * acc[u];
    }
    #pragma unroll
    for (int off = 16; off; off >>= 1) {
        s1 += __shfl_xor(s1, off, 64);
        s2 += __shfl_xor(s2, off, 64);
    }
    const float mean = s1 * (1.0f / FOUT);
    const float var  = s2 * (1.0f / FOUT) - mean * mean;
    const float rstd = rsqrtf(var + EPSV);

    const float4 g0 = *(const float4*)(gamma + f0);
    const float4 g1 = *(const float4*)(gamma + f0 + 4);
    const float4 b0 = *(const float4*)(beta  + f0);
    const float4 b1 = *(const float4*)(beta  + f0 + 4);
    float* orow = out + ((long)(b * N_ + i0 + r)) * FOUT + f0;
    float4 o0, o1;
    o0.x = gelu_exact((acc[0] - mean) * rstd * g0.x + b0.x);
    o0.y = gelu_exact((acc[1] - mean) * rstd * g0.y + b0.y);
    o0.z = gelu_exact((acc[2] - mean) * rstd * g0.z + b0.z);
    o0.w = gelu_exact((acc[3] - mean) * rstd * g0.w + b0.w);
    o1.x = gelu_exact((acc[4] - mean) * rstd * g1.x + b1.x);
    o1.y = gelu_exact((acc[5] - mean) * rstd * g1.y + b1.y);
    o1.z = gelu_exact((acc[6] - mean) * rstd * g1.z + b1.z);
    o1.w = gelu_exact((acc[7] - mean) * rstd * g1.w + b1.w);
    *(float4*)(orow)     = o0;
    *(float4*)(orow + 4) = o1;
}

extern "C" void kernel_launch(void* const* d_in, const int* in_sizes, int n_in,
                              void* d_out, int out_size, void* d_ws, size_t ws_size,
                              hipStream_t stream) {
    const float* h     = (const float*)d_in[0];
    const float* adj   = (const float*)d_in[1];
    // d_in[2]=q_type, d_in[3]=pos : unused scalars
    const float* W     = (const float*)d_in[4];
    const float* a     = (const float*)d_in[5];
    const float* gamma = (const float*)d_in[6];
    const float* beta  = (const float*)d_in[7];
    float* out = (float*)d_out;

    float* Wh = (float*)d_ws;                     // 8192*256 floats
    float* F1 = Wh + (size_t)B_ * N_ * FOUT;      // 8192 floats
    float* F2 = F1 + (size_t)B_ * N_;             // 8192 floats

    k_gemm<<<dim3(B_ * N_ / BM), 256, 0, stream>>>(h, W, a, Wh, F1, F2);
    k_attn<<<dim3(N_ / 8, B_), 256, 0, stream>>>(Wh, adj, F1, F2, gamma, beta, out);
}

// Round 3
// 85.556 us; speedup vs baseline: 6.0720x; 1.0134x over previous
//
#include <hip/hip_runtime.h>
#include <math.h>

#define B_    8
#define N_    1024
#define FIN   512
#define FOUT  256
#define ALPHA 0.2f
#define NEGV  (-9.0e15f)
#define EPSV  1e-5f

typedef __attribute__((ext_vector_type(8))) short bf16x8;
typedef __attribute__((ext_vector_type(4))) float f32x4;

__device__ __forceinline__ short f2bf(float x) {
    unsigned u = __builtin_bit_cast(unsigned, x);
    u = (u + 0x7FFFu + ((u >> 16) & 1u)) >> 16;
    return (short)u;
}
__device__ __forceinline__ float gelu_exact(float x) {
    return 0.5f * x * (1.0f + erff(x * 0.70710678118654752f));
}

// ---------------------------------------------------------------------------
// k_prep: W (512x256 fp32 row-major) -> WT (256x512 bf16, [col][k]).
// ---------------------------------------------------------------------------
__global__ __launch_bounds__(256) void k_prep(const float* __restrict__ W,
                                              short* __restrict__ WT) {
    int id  = blockIdx.x * 256 + threadIdx.x;   // 32768 threads, 4 elems each
    int col = id >> 7;
    int k4  = (id & 127) * 4;
    short4 v;
    v.x = f2bf(W[(k4 + 0) * FOUT + col]);
    v.y = f2bf(W[(k4 + 1) * FOUT + col]);
    v.z = f2bf(W[(k4 + 2) * FOUT + col]);
    v.w = f2bf(W[(k4 + 3) * FOUT + col]);
    *(short4*)(WT + (long)col * FIN + k4) = v;
}

// ---------------------------------------------------------------------------
// k_wh: Wh = h @ W via bf16 MFMA (16x16x32). Block = 256 thr (4 waves),
// BM = 16 rows; wave w -> cols w*64..+63 (4 col-frags). Grid = 512.
// A-frags from fp32 h (cvt in reg), B-frags from WT bf16 (L1-resident).
// Writes WhT bf16 ([b][col][row]) + fused F1/F2.
// C/D layout: col = lane&15, row = (lane>>4)*4 + j  [m89-verified].
// ---------------------------------------------------------------------------
__global__ __launch_bounds__(256) void k_wh(const float* __restrict__ h,
                                            const short* __restrict__ WT,
                                            const float* __restrict__ a,
                                            short* __restrict__ WhT,
                                            float* __restrict__ F1,
                                            float* __restrict__ F2) {
    const int tid = threadIdx.x;
    const int w   = tid >> 6, l = tid & 63;
    const int lr  = l & 15, lq = l >> 4;
    const long row0 = (long)blockIdx.x * 16;
    const int colbase = w * 64;

    __shared__ float r1[4][16], r2[4][16];

    f32x4 acc[4] = {};

    const float* hrow = h + (row0 + lr) * FIN + lq * 8;

    for (int k0 = 0; k0 < FIN; k0 += 32) {
        float4 v0 = *(const float4*)(hrow + k0);
        float4 v1 = *(const float4*)(hrow + k0 + 4);
        bf16x8 af;
        af[0] = f2bf(v0.x); af[1] = f2bf(v0.y); af[2] = f2bf(v0.z); af[3] = f2bf(v0.w);
        af[4] = f2bf(v1.x); af[5] = f2bf(v1.y); af[6] = f2bf(v1.z); af[7] = f2bf(v1.w);
        #pragma unroll
        for (int c = 0; c < 4; ++c) {
            const short* bp = WT + (long)(colbase + c * 16 + lr) * FIN + k0 + lq * 8;
            bf16x8 bf = *(const bf16x8*)bp;
            acc[c] = __builtin_amdgcn_mfma_f32_16x16x32_bf16(af, bf, acc[c], 0, 0, 0);
        }
    }

    const int b   = (int)(row0 >> 10);
    const int il0 = (int)(row0 & 1023);

    // transposed Wh store: 4 consecutive rows (j) at fixed col -> one short4
    #pragma unroll
    for (int c = 0; c < 4; ++c) {
        short4 s;
        s.x = f2bf(acc[c][0]); s.y = f2bf(acc[c][1]);
        s.z = f2bf(acc[c][2]); s.w = f2bf(acc[c][3]);
        int col = colbase + c * 16 + lr;
        *(short4*)(WhT + ((long)b * FOUT + col) * N_ + il0 + lq * 4) = s;
    }

    // fused F1/F2 (this wave's 64-col partial, then cross-wave LDS reduce)
    float p1[4] = {0.f, 0.f, 0.f, 0.f}, p2[4] = {0.f, 0.f, 0.f, 0.f};
    #pragma unroll
    for (int c = 0; c < 4; ++c) {
        int col = colbase + c * 16 + lr;
        float a1v = a[col], a2v = a[FOUT + col];
        #pragma unroll
        for (int j = 0; j < 4; ++j) { p1[j] += acc[c][j] * a1v; p2[j] += acc[c][j] * a2v; }
    }
    #pragma unroll
    for (int off = 1; off < 16; off <<= 1) {
        #pragma unroll
        for (int j = 0; j < 4; ++j) {
            p1[j] += __shfl_xor(p1[j], off, 64);
            p2[j] += __shfl_xor(p2[j], off, 64);
        }
    }
    if (lr == 0) {
        #pragma unroll
        for (int j = 0; j < 4; ++j) { r1[w][lq * 4 + j] = p1[j]; r2[w][lq * 4 + j] = p2[j]; }
    }
    __syncthreads();
    if (tid < 16) {
        F1[row0 + tid] = r1[0][tid] + r1[1][tid] + r1[2][tid] + r1[3][tid];
        F2[row0 + tid] = r2[0][tid] + r2[1][tid] + r2[2][tid] + r2[3][tid];
    }
}

// ---------------------------------------------------------------------------
// k_attn: fused flash-style attention. Block = 512 thr (8 waves), 32 rows.
// Grid = (32, 8). Per 64-j chunk: P-gen (masked leaky logits, online m/l,
// exp -> bf16 Ps in LDS) -> barrier -> MFMA (rescale acc, P @ WhT frags).
// Wave w: rows (w>>2)*16..+15, cols (w&3)*64..+63.
// Epilogue: 1/l scale, LayerNorm (cross-wave LDS reduce), exact GELU.
// Masked entries: exp(NEGV - m) == 0; all-masked row: m=NEGV -> exp(0)=1,
// l=1024 -> uniform 1/N, exactly matching the reference softmax.
// ---------------------------------------------------------------------------
__global__ __launch_bounds__(512) void k_attn(const short* __restrict__ WhT,
                                              const float* __restrict__ adj,
                                              const float* __restrict__ F1,
                                              const float* __restrict__ F2,
                                              const float* __restrict__ gamma,
                                              const float* __restrict__ beta,
                                              float* __restrict__ out) {
    const int tid = threadIdx.x;
    const int b   = blockIdx.y;
    const int i0  = blockIdx.x * 32;

    __shared__ float f2s[N_];                       // 4 KB
    __shared__ float f1s[32], m_s[32], l_s[32], fs_s[32];
    __shared__ short Ps[32][72];                    // 4.6 KB, pad 8 -> row stride 144B
    __shared__ float r1[4][32], r2[4][32];          // LN partials

    if (tid < 256) *(float4*)&f2s[tid * 4] = *(const float4*)(F2 + b * N_ + tid * 4);
    if (tid < 32) { f1s[tid] = F1[b * N_ + i0 + tid]; m_s[tid] = -INFINITY; l_s[tid] = 0.f; }
    __syncthreads();

    const int w   = tid >> 6, l = tid & 63;
    const int lr  = l & 15, lq = l >> 4;
    const int rw0 = (w >> 2) * 16;
    const int cw0 = (w & 3) * 64;

    const int pr = tid >> 4;     // P-gen: row 0..31
    const int ps = tid & 15;     // P-gen: 16 lanes per row, 4 j's each
    const float f1v = f1s[pr];
    const float* __restrict__ arow = adj + ((long)b * N_ + i0 + pr) * N_;
    const short* __restrict__ whtb = WhT + (long)b * FOUT * N_;

    f32x4 acc[4] = {};

    for (int k0 = 0; k0 < N_; k0 += 64) {
        // ---- P-gen ----
        float4 av = *(const float4*)(arow + k0 + ps * 4);
        float aa[4] = {av.x, av.y, av.z, av.w};
        float x[4];
        float cmax = -INFINITY;
        #pragma unroll
        for (int u = 0; u < 4; ++u) {
            float t = f1v + f2s[k0 + ps * 4 + u];
            t = (t > 0.f) ? t : ALPHA * t;
            x[u] = (aa[u] > 0.f) ? t : NEGV;
            cmax = fmaxf(cmax, x[u]);
        }
        #pragma unroll
        for (int off = 1; off < 16; off <<= 1) cmax = fmaxf(cmax, __shfl_xor(cmax, off, 64));
        const float m_old = m_s[pr];               // same-wave read-before-write
        const float m_new = fmaxf(m_old, cmax);
        float p[4], psum = 0.f;
        #pragma unroll
        for (int u = 0; u < 4; ++u) { p[u] = __expf(x[u] - m_new); psum += p[u]; }
        #pragma unroll
        for (int off = 1; off < 16; off <<= 1) psum += __shfl_xor(psum, off, 64);
        if (ps == 0) {
            float fs = __expf(m_old - m_new);
            l_s[pr]  = l_s[pr] * fs + psum;
            m_s[pr]  = m_new;
            fs_s[pr] = fs;
        }
        short4 pb;
        pb.x = f2bf(p[0]); pb.y = f2bf(p[1]); pb.z = f2bf(p[2]); pb.w = f2bf(p[3]);
        *(short4*)&Ps[pr][ps * 4] = pb;
        __syncthreads();

        // ---- MFMA: rescale + P @ WhT ----
        float fsv[4];
        #pragma unroll
        for (int j = 0; j < 4; ++j) fsv[j] = fs_s[rw0 + lq * 4 + j];
        #pragma unroll
        for (int c = 0; c < 4; ++c) {
            #pragma unroll
            for (int j = 0; j < 4; ++j) acc[c][j] *= fsv[j];
        }
        #pragma unroll
        for (int kq = 0; kq < 2; ++kq) {
            bf16x8 af = *(const bf16x8*)&Ps[rw0 + lr][kq * 32 + lq * 8];
            #pragma unroll
            for (int c = 0; c < 4; ++c) {
                const short* bp = whtb + (long)(cw0 + c * 16 + lr) * N_ + k0 + kq * 32 + lq * 8;
                bf16x8 bf = *(const bf16x8*)bp;
                acc[c] = __builtin_amdgcn_mfma_f32_16x16x32_bf16(af, bf, acc[c], 0, 0, 0);
            }
        }
        __syncthreads();
    }

    // ---- epilogue: 1/l, LayerNorm across 256 cols, GELU ----
    float il[4];
    #pragma unroll
    for (int j = 0; j < 4; ++j) il[j] = 1.0f / l_s[rw0 + lq * 4 + j];
    float s1[4] = {0.f, 0.f, 0.f, 0.f}, s2[4] = {0.f, 0.f, 0.f, 0.f};
    #pragma unroll
    for (int c = 0; c < 4; ++c) {
        #pragma unroll
        for (int j = 0; j < 4; ++j) {
            acc[c][j] *= il[j];
            s1[j] += acc[c][j];
            s2[j] += acc[c][j] * acc[c][j];
        }
    }
    #pragma unroll
    for (int off = 1; off < 16; off <<= 1) {
        #pragma unroll
        for (int j = 0; j < 4; ++j) {
            s1[j] += __shfl_xor(s1[j], off, 64);
            s2[j] += __shfl_xor(s2[j], off, 64);
        }
    }
    if (lr == 0) {
        #pragma unroll
        for (int j = 0; j < 4; ++j) {
            r1[w & 3][rw0 + lq * 4 + j] = s1[j];
            r2[w & 3][rw0 + lq * 4 + j] = s2[j];
        }
    }
    __syncthreads();

    #pragma unroll
    for (int c = 0; c < 4; ++c) {
        int col = cw0 + c * 16 + lr;
        float g = gamma[col], bt = beta[col];
        #pragma unroll
        for (int j = 0; j < 4; ++j) {
            int row = rw0 + lq * 4 + j;
            float t1 = r1[0][row] + r1[1][row] + r1[2][row] + r1[3][row];
            float t2 = r2[0][row] + r2[1][row] + r2[2][row] + r2[3][row];
            float mu = t1 * (1.0f / FOUT);
            float rstd = rsqrtf(t2 * (1.0f / FOUT) - mu * mu + EPSV);
            out[((long)b * N_ + i0 + row) * FOUT + col] =
                gelu_exact((acc[c][j] - mu) * rstd * g + bt);
        }
    }
}

extern "C" void kernel_launch(void* const* d_in, const int* in_sizes, int n_in,
                              void* d_out, int out_size, void* d_ws, size_t ws_size,
                              hipStream_t stream) {
    const float* h     = (const float*)d_in[0];
    const float* adj   = (const float*)d_in[1];
    // d_in[2]=q_type, d_in[3]=pos : unused scalars
    const float* W     = (const float*)d_in[4];
    const float* a     = (const float*)d_in[5];
    const float* gamma = (const float*)d_in[6];
    const float* beta  = (const float*)d_in[7];
    float* out = (float*)d_out;

    short* WhT = (short*)d_ws;                         // 8*256*1024 bf16 = 4 MB
    short* WT  = WhT + (size_t)B_ * FOUT * N_;         // 256*512 bf16 = 256 KB
    float* F1  = (float*)(WT + (size_t)FOUT * FIN);    // 8192 fp32
    float* F2  = F1 + (size_t)B_ * N_;                 // 8192 fp32

    k_prep<<<dim3(128), 256, 0, stream>>>(W, WT);
    k_wh<<<dim3(B_ * N_ / 16), 256, 0, stream>>>(h, WT, a, WhT, F1, F2);
    k_attn<<<dim3(N_ / 32, B_), 512, 0, stream>>>(WhT, adj, F1, F2, gamma, beta, out);
}